// Round 1
// baseline (442.567 us; speedup 1.0000x reference)
//
#include <hip/hip_runtime.h>
#include <cstddef>

#define F_DIM 39
#define E_DIM 32
#define B_DIM 16384
#define CHUNKS 64
#define ROWS_PER_BLOCK (B_DIM / CHUNKS)   // 256 rows per block, 8 groups -> 32 steps
#define EPS_BN 1e-5f
#define EPS_G 1e-10f

// workspace layout (floats):
//   [0,      39936) : C[f][i][j]      (39*1024)  -- zeroed each launch
//   [39936,  41184) : S1[f][i]        (39*32)    -- zeroed each launch
//   [41184,  41312) : sum1[c][e]      (4*32)     -- zeroed each launch
//   [41312,  41440) : sum2[c][e]      (4*32)     -- zeroed each launch
//   [41440,  81376) : Weff[f][i][e]   (39*1024)  -- fully overwritten
//   [81376,  82624) : bias[f][e]      (39*32)    -- fully overwritten

// ---------------- pass 1: sufficient statistics over B ----------------
__global__ __launch_bounds__(256) void k_stats(const float* __restrict__ emb,
                                               float* __restrict__ Cbuf,
                                               float* __restrict__ S1buf) {
    const int f = blockIdx.y;
    const int chunk = blockIdx.x;
    const int tid = threadIdx.x;
    const int grp = tid >> 5;
    const int lane = tid & 31;

    float acc[32];
#pragma unroll
    for (int i = 0; i < 32; ++i) acc[i] = 0.f;
    float s1 = 0.f;

    const int b0 = chunk * ROWS_PER_BLOCK;
    for (int s = 0; s < ROWS_PER_BLOCK / 8; ++s) {
        const int b = b0 + s * 8 + grp;
        const float v = emb[((size_t)b * F_DIM + f) * E_DIM + lane];
        s1 += v;
#pragma unroll
        for (int i = 0; i < 32; ++i) {
            const float vi = __shfl(v, i, 32);   // broadcast within 32-lane group
            acc[i] = fmaf(vi, v, acc[i]);
        }
    }

    __shared__ float ldsC[1024];
    __shared__ float ldsS[32];
    for (int idx = tid; idx < 1024; idx += 256) ldsC[idx] = 0.f;
    if (tid < 32) ldsS[tid] = 0.f;
    __syncthreads();
#pragma unroll
    for (int i = 0; i < 32; ++i) atomicAdd(&ldsC[i * 32 + lane], acc[i]);
    atomicAdd(&ldsS[lane], s1);
    __syncthreads();
    for (int idx = tid; idx < 1024; idx += 256)
        unsafeAtomicAdd(&Cbuf[f * 1024 + idx], ldsC[idx]);
    if (tid < 32) unsafeAtomicAdd(&S1buf[f * 32 + tid], ldsS[tid]);
}

// ------------- glue A: per-f quadratic forms -> per-(c,e) sums -------------
__global__ __launch_bounds__(128) void k_reduce_stats(
    const float* __restrict__ Cbuf, const float* __restrict__ S1buf,
    const float* __restrict__ w4, const float* __restrict__ w8,
    const float* __restrict__ w16, const float* __restrict__ w32,
    float* __restrict__ sum1, float* __restrict__ sum2) {
    const int f = blockIdx.x;
    const int tid = threadIdx.x;
    const int c = tid >> 5;      // candidate 0..3
    const int e = tid & 31;      // channel

    __shared__ float ldsC[1024];
    __shared__ float ldsS[32];
    for (int idx = tid; idx < 1024; idx += 128) ldsC[idx] = Cbuf[f * 1024 + idx];
    if (tid < 32) ldsS[tid] = S1buf[f * 32 + tid];
    __syncthreads();

    const int d = 4 << c;
    const float* w = (c == 0) ? w4 : (c == 1) ? w8 : (c == 2) ? w16 : w32;
    w += (size_t)f * d * E_DIM;

    float wcol[32];
#pragma unroll
    for (int i = 0; i < 32; ++i)
        wcol[i] = (i < d) ? w[(size_t)i * E_DIM + e] : 0.f;

    float m1 = 0.f;
#pragma unroll
    for (int i = 0; i < 32; ++i) m1 = fmaf(ldsS[i], wcol[i], m1);

    float m2 = 0.f;
#pragma unroll
    for (int i = 0; i < 32; ++i) {
        float ti = 0.f;
#pragma unroll
        for (int j = 0; j < 32; ++j) ti = fmaf(ldsC[i * 32 + j], wcol[j], ti);
        m2 = fmaf(ti, wcol[i], m2);
    }
    unsafeAtomicAdd(&sum1[c * 32 + e], m1);
    unsafeAtomicAdd(&sum2[c * 32 + e], m2);
}

// ------------- glue B: finalize stats, gumbel gates, build W_eff/bias -------------
__global__ __launch_bounds__(256) void k_finalize(
    const float* __restrict__ sum1, const float* __restrict__ sum2,
    const float* __restrict__ gate, const float* __restrict__ noise,
    const float* __restrict__ w4, const float* __restrict__ w8,
    const float* __restrict__ w16, const float* __restrict__ w32,
    float* __restrict__ Weff, float* __restrict__ biasb) {
    const int tid = threadIdx.x;
    __shared__ float inv_s[4][32];
    __shared__ float mu_s[4][32];
    __shared__ float gate_s[39][4];   // includes the 1/4 "mean over candidates"

    if (tid < 128) {
        const int c = tid >> 5, e = tid & 31;
        const float invBF = 1.0f / ((float)B_DIM * (float)F_DIM);
        const float mu = sum1[tid] * invBF;
        const float ey2 = sum2[tid] * invBF;
        const float var = ey2 - mu * mu;
        inv_s[c][e] = rsqrtf(var + EPS_BN);
        mu_s[c][e] = mu;
    }
    if (tid < F_DIM) {
        float l[4], mx = -1e30f;
#pragma unroll
        for (int c = 0; c < 4; ++c) {
            const float u = noise[tid * 4 + c];
            const float g = -logf(-logf(u + EPS_G) + EPS_G);
            l[c] = gate[tid * 4 + c] + g;      // tau = 1
            mx = fmaxf(mx, l[c]);
        }
        float se = 0.f;
#pragma unroll
        for (int c = 0; c < 4; ++c) { l[c] = expf(l[c] - mx); se += l[c]; }
#pragma unroll
        for (int c = 0; c < 4; ++c) gate_s[tid][c] = 0.25f * l[c] / se;
    }
    __syncthreads();

    for (int idx = tid; idx < F_DIM * 1024; idx += 256) {
        const int f = idx >> 10;
        const int i = (idx >> 5) & 31;
        const int e = idx & 31;
        float acc = 0.f;
#pragma unroll
        for (int c = 0; c < 4; ++c) {
            const int d = 4 << c;
            if (i < d) {
                const float* w = (c == 0) ? w4 : (c == 1) ? w8 : (c == 2) ? w16 : w32;
                acc = fmaf(gate_s[f][c] * inv_s[c][e],
                           w[((size_t)f * d + i) * E_DIM + e], acc);
            }
        }
        Weff[idx] = acc;
    }
    for (int idx = tid; idx < F_DIM * E_DIM; idx += 256) {
        const int f = idx >> 5, e = idx & 31;
        float acc = 0.f;
#pragma unroll
        for (int c = 0; c < 4; ++c)
            acc = fmaf(gate_s[f][c], inv_s[c][e] * mu_s[c][e], acc);
        biasb[idx] = acc;
    }
}

// ---------------- pass 2: single fused affine map ----------------
__global__ __launch_bounds__(256) void k_apply(const float* __restrict__ emb,
                                               const float* __restrict__ Weff,
                                               const float* __restrict__ biasb,
                                               float* __restrict__ out) {
    const int f = blockIdx.y;
    const int chunk = blockIdx.x;
    const int tid = threadIdx.x;
    const int grp = tid >> 5;
    const int lane = tid & 31;

    float wcol[32];
#pragma unroll
    for (int i = 0; i < 32; ++i) wcol[i] = Weff[f * 1024 + i * 32 + lane];
    const float be = biasb[f * 32 + lane];

    const int b0 = chunk * ROWS_PER_BLOCK;
    for (int s = 0; s < ROWS_PER_BLOCK / 8; ++s) {
        const int b = b0 + s * 8 + grp;
        const size_t off = ((size_t)b * F_DIM + f) * E_DIM;
        const float v = emb[off + lane];
        float o = -be;
#pragma unroll
        for (int i = 0; i < 32; ++i) {
            const float vi = __shfl(v, i, 32);
            o = fmaf(vi, wcol[i], o);
        }
        out[off + lane] = o;
    }
}

extern "C" void kernel_launch(void* const* d_in, const int* in_sizes, int n_in,
                              void* d_out, int out_size, void* d_ws, size_t ws_size,
                              hipStream_t stream) {
    const float* emb   = (const float*)d_in[0];
    const float* w4    = (const float*)d_in[1];
    const float* w8    = (const float*)d_in[2];
    const float* w16   = (const float*)d_in[3];
    const float* w32   = (const float*)d_in[4];
    const float* gate  = (const float*)d_in[5];
    const float* noise = (const float*)d_in[6];
    float* out = (float*)d_out;

    float* ws    = (float*)d_ws;
    float* Cbuf  = ws;            // 39936
    float* S1buf = ws + 39936;    // 1248
    float* sum1  = ws + 41184;    // 128
    float* sum2  = ws + 41312;    // 128
    float* Weff  = ws + 41440;    // 39936
    float* biasb = ws + 81376;    // 1248

    hipMemsetAsync(d_ws, 0, 41440 * sizeof(float), stream);
    k_stats<<<dim3(CHUNKS, F_DIM), 256, 0, stream>>>(emb, Cbuf, S1buf);
    k_reduce_stats<<<F_DIM, 128, 0, stream>>>(Cbuf, S1buf, w4, w8, w16, w32, sum1, sum2);
    k_finalize<<<1, 256, 0, stream>>>(sum1, sum2, gate, noise, w4, w8, w16, w32, Weff, biasb);
    k_apply<<<dim3(CHUNKS, F_DIM), 256, 0, stream>>>(emb, Weff, biasb, out);
}

// Round 2
// 119.584 us; speedup vs baseline: 3.7009x; 3.7009x over previous
//
#include <hip/hip_runtime.h>
#include <cstdint>
#include <cstddef>

#define F_DIM 39
#define E_DIM 32
#define B_DIM 16384
#define ROWSTRIDE (F_DIM * E_DIM)   // 1248 floats per b row
#define EPS_BN 1e-5f
#define EPS_G 1e-10f

typedef _Float16 f16x8 __attribute__((ext_vector_type(8)));
typedef float f32x16 __attribute__((ext_vector_type(16)));

union H8 { _Float16 h[8]; f16x8 v; uint32_t u[4]; };

// workspace layout (float units):
//   [0,      39936) : C[f][i][j]   (39*1024)  -- zeroed each launch
//   [39936,  41184) : S1[f][i]     (39*32)    -- zeroed each launch
//   [41184,  41312) : sum1[c][e]   (4*32)     -- zeroed each launch
//   [41312,  41440) : sum2[c][e]   (4*32)     -- zeroed each launch
//   [41440,  61408) : Whp[f][16][32] packed f16-hi pairs (uint32)
//   [61408,  81376) : Wlp[f][16][32] packed f16-lo pairs (uint32)
//   [81376,  82624) : bias[f][e]   (39*32)

// ---------------- pass 1: C_f = X_f^T X_f via MFMA (f16 split) ----------------
#define S_CHUNKS 32
#define S_RPB (B_DIM / S_CHUNKS)     // 512 rows/block; 128 rows/wave; 8 K-steps of 16

__global__ __launch_bounds__(256) void k_stats(const float* __restrict__ emb,
                                               float* __restrict__ Cbuf,
                                               float* __restrict__ S1buf) {
    const int f = blockIdx.y;
    const int tid = threadIdx.x;
    const int wave = tid >> 6;
    const int l = tid & 63;
    const int g = l >> 5;        // half-wave (k-group)
    const int c = l & 31;        // column i of X (= m and n of MFMA)

    __shared__ float ldsC[4][1024];

    f32x16 acc;
#pragma unroll
    for (int i = 0; i < 16; ++i) acc[i] = 0.f;
    float s1 = 0.f;

    const int rbase = blockIdx.x * S_RPB + wave * (S_RPB / 4);
    const float* p = emb + (size_t)(rbase + 8 * g) * ROWSTRIDE + f * E_DIM + c;

    for (int t = 0; t < (S_RPB / 4) / 16; ++t) {   // 8 steps, 16 rows each
        float x[8];
#pragma unroll
        for (int e = 0; e < 8; ++e) x[e] = p[(size_t)e * ROWSTRIDE];
        H8 fh, fl;
#pragma unroll
        for (int e = 0; e < 8; ++e) {
            const _Float16 hh = (_Float16)x[e];
            fh.h[e] = hh;
            fl.h[e] = (_Float16)(x[e] - (float)hh);
            s1 += x[e];
        }
        // same fragment feeds A and B: C += Xh^T Xh + Xh^T Xl + Xl^T Xh
        acc = __builtin_amdgcn_mfma_f32_32x32x16_f16(fh.v, fh.v, acc, 0, 0, 0);
        acc = __builtin_amdgcn_mfma_f32_32x32x16_f16(fh.v, fl.v, acc, 0, 0, 0);
        acc = __builtin_amdgcn_mfma_f32_32x32x16_f16(fl.v, fh.v, acc, 0, 0, 0);
        p += (size_t)16 * ROWSTRIDE;
    }

    // D layout (HW-verified): col = lane&31, row = (r&3) + 8*(r>>2) + 4*(lane>>5)
#pragma unroll
    for (int r = 0; r < 16; ++r) {
        const int mrow = (r & 3) + 8 * (r >> 2) + 4 * g;
        ldsC[wave][mrow * 32 + c] = acc[r];
    }
    s1 += __shfl_xor(s1, 32, 64);
    __syncthreads();
    for (int idx = tid; idx < 1024; idx += 256) {
        const float s = ldsC[0][idx] + ldsC[1][idx] + ldsC[2][idx] + ldsC[3][idx];
        unsafeAtomicAdd(&Cbuf[f * 1024 + idx], s);
    }
    if (l < 32) unsafeAtomicAdd(&S1buf[f * 32 + c], s1);
}

// ------------- glue A: per-f quadratic forms -> per-(c,e) sums -------------
__global__ __launch_bounds__(128) void k_reduce_stats(
    const float* __restrict__ Cbuf, const float* __restrict__ S1buf,
    const float* __restrict__ w4, const float* __restrict__ w8,
    const float* __restrict__ w16, const float* __restrict__ w32,
    float* __restrict__ sum1, float* __restrict__ sum2) {
    const int f = blockIdx.x;
    const int tid = threadIdx.x;
    const int cc = tid >> 5;
    const int e = tid & 31;

    __shared__ float ldsC[1024];
    __shared__ float ldsS[32];
    for (int idx = tid; idx < 1024; idx += 128) ldsC[idx] = Cbuf[f * 1024 + idx];
    if (tid < 32) ldsS[tid] = S1buf[f * 32 + tid];
    __syncthreads();

    const int d = 4 << cc;
    const float* w = (cc == 0) ? w4 : (cc == 1) ? w8 : (cc == 2) ? w16 : w32;
    w += (size_t)f * d * E_DIM;

    float wcol[32];
#pragma unroll
    for (int i = 0; i < 32; ++i)
        wcol[i] = (i < d) ? w[(size_t)i * E_DIM + e] : 0.f;

    float m1 = 0.f;
#pragma unroll
    for (int i = 0; i < 32; ++i) m1 = fmaf(ldsS[i], wcol[i], m1);

    float m2 = 0.f;
#pragma unroll
    for (int i = 0; i < 32; ++i) {
        float ti = 0.f;
#pragma unroll
        for (int j = 0; j < 32; ++j) ti = fmaf(ldsC[i * 32 + j], wcol[j], ti);
        m2 = fmaf(ti, wcol[i], m2);
    }
    unsafeAtomicAdd(&sum1[cc * 32 + e], m1);
    unsafeAtomicAdd(&sum2[cc * 32 + e], m2);
}

// ------------- glue B: stats + gumbel gates -> packed f16 W_eff + bias -------------
__global__ __launch_bounds__(256) void k_finalize(
    const float* __restrict__ sum1, const float* __restrict__ sum2,
    const float* __restrict__ gate, const float* __restrict__ noise,
    const float* __restrict__ w4, const float* __restrict__ w8,
    const float* __restrict__ w16, const float* __restrict__ w32,
    uint32_t* __restrict__ Whp, uint32_t* __restrict__ Wlp,
    float* __restrict__ biasb) {
    const int tid = threadIdx.x;
    __shared__ float inv_s[4][32];
    __shared__ float mu_s[4][32];
    __shared__ float gate_s[39][4];

    if (tid < 128) {
        const int cc = tid >> 5, e = tid & 31;
        const float invBF = 1.0f / ((float)B_DIM * (float)F_DIM);
        const float mu = sum1[tid] * invBF;
        const float ey2 = sum2[tid] * invBF;
        const float var = ey2 - mu * mu;
        inv_s[cc][e] = rsqrtf(var + EPS_BN);
        mu_s[cc][e] = mu;
    }
    if (tid < F_DIM) {
        float lg[4], mx = -1e30f;
#pragma unroll
        for (int cc = 0; cc < 4; ++cc) {
            const float u = noise[tid * 4 + cc];
            const float gg = -logf(-logf(u + EPS_G) + EPS_G);
            lg[cc] = gate[tid * 4 + cc] + gg;
            mx = fmaxf(mx, lg[cc]);
        }
        float se = 0.f;
#pragma unroll
        for (int cc = 0; cc < 4; ++cc) { lg[cc] = expf(lg[cc] - mx); se += lg[cc]; }
#pragma unroll
        for (int cc = 0; cc < 4; ++cc) gate_s[tid][cc] = 0.25f * lg[cc] / se;
    }
    __syncthreads();

    // Weff[f][i][e] packed as (i even, i odd) f16 pairs, split hi/lo
    for (int idx = tid; idx < F_DIM * 512; idx += 256) {
        const int f = idx >> 9;
        const int kp = (idx >> 5) & 15;
        const int e = idx & 31;
        const int i0 = kp * 2;
        float w0 = 0.f, w1 = 0.f;
#pragma unroll
        for (int cc = 0; cc < 4; ++cc) {
            const int d = 4 << cc;
            if (i0 < d) {
                const float* w = (cc == 0) ? w4 : (cc == 1) ? w8 : (cc == 2) ? w16 : w32;
                const float gi = gate_s[f][cc] * inv_s[cc][e];
                const size_t base = ((size_t)f * d + i0) * E_DIM + e;
                w0 = fmaf(gi, w[base], w0);
                w1 = fmaf(gi, w[base + E_DIM], w1);
            }
        }
        union { _Float16 h[2]; uint32_t u; } ph, pl;
        const _Float16 h0 = (_Float16)w0, h1 = (_Float16)w1;
        ph.h[0] = h0; ph.h[1] = h1;
        pl.h[0] = (_Float16)(w0 - (float)h0);
        pl.h[1] = (_Float16)(w1 - (float)h1);
        Whp[idx] = ph.u;
        Wlp[idx] = pl.u;
    }
    for (int idx = tid; idx < F_DIM * E_DIM; idx += 256) {
        const int f = idx >> 5, e = idx & 31;
        float a = 0.f;
#pragma unroll
        for (int cc = 0; cc < 4; ++cc)
            a = fmaf(gate_s[f][cc], inv_s[cc][e] * mu_s[cc][e], a);
        biasb[idx] = a;
    }
}

// ---------------- pass 2: Out_f = X_f * Weff_f - bias via MFMA ----------------
#define A_CHUNKS 64
#define A_RPB (B_DIM / A_CHUNKS)    // 256 rows/block; 64/wave = 2 tiles of 32

__global__ __launch_bounds__(256) void k_apply(const float* __restrict__ emb,
                                               const uint32_t* __restrict__ Whp,
                                               const uint32_t* __restrict__ Wlp,
                                               const float* __restrict__ biasb,
                                               float* __restrict__ out) {
    const int f = blockIdx.y;
    const int tid = threadIdx.x;
    const int wave = tid >> 6;
    const int l = tid & 63;
    const int g = l >> 5;
    const int c = l & 31;        // m (b-row in tile) for A, n (=e) for B/D

    // B-operand fragments: k = 16q + 8g + 2p + h  <->  Whp word kp = 8q + 4g + p
    H8 wh[2], wl[2];
#pragma unroll
    for (int q = 0; q < 2; ++q)
#pragma unroll
        for (int pp = 0; pp < 4; ++pp) {
            const int kp = 8 * q + 4 * g + pp;
            wh[q].u[pp] = Whp[f * 512 + kp * 32 + c];
            wl[q].u[pp] = Wlp[f * 512 + kp * 32 + c];
        }
    const float be = biasb[f * 32 + c];

    const int wbase = blockIdx.x * A_RPB + wave * (A_RPB / 4);
#pragma unroll
    for (int t = 0; t < (A_RPB / 4) / 32; ++t) {
        const int b0 = wbase + t * 32;
        const float4* pa = reinterpret_cast<const float4*>(
            emb + (size_t)(b0 + c) * ROWSTRIDE + f * E_DIM + 8 * g);
        f32x16 acc;
#pragma unroll
        for (int i = 0; i < 16; ++i) acc[i] = 0.f;
#pragma unroll
        for (int q = 0; q < 2; ++q) {
            const float4 v0 = pa[4 * q];
            const float4 v1 = pa[4 * q + 1];
            const float x[8] = {v0.x, v0.y, v0.z, v0.w, v1.x, v1.y, v1.z, v1.w};
            H8 ah, al;
#pragma unroll
            for (int e = 0; e < 8; ++e) {
                const _Float16 hh = (_Float16)x[e];
                ah.h[e] = hh;
                al.h[e] = (_Float16)(x[e] - (float)hh);
            }
            acc = __builtin_amdgcn_mfma_f32_32x32x16_f16(ah.v, wh[q].v, acc, 0, 0, 0);
            acc = __builtin_amdgcn_mfma_f32_32x32x16_f16(ah.v, wl[q].v, acc, 0, 0, 0);
            acc = __builtin_amdgcn_mfma_f32_32x32x16_f16(al.v, wh[q].v, acc, 0, 0, 0);
        }
        float* po = out + (size_t)b0 * ROWSTRIDE + f * E_DIM + c;
#pragma unroll
        for (int r = 0; r < 16; ++r) {
            const int mrow = (r & 3) + 8 * (r >> 2) + 4 * g;
            po[(size_t)mrow * ROWSTRIDE] = acc[r] - be;
        }
    }
}

extern "C" void kernel_launch(void* const* d_in, const int* in_sizes, int n_in,
                              void* d_out, int out_size, void* d_ws, size_t ws_size,
                              hipStream_t stream) {
    const float* emb   = (const float*)d_in[0];
    const float* w4    = (const float*)d_in[1];
    const float* w8    = (const float*)d_in[2];
    const float* w16   = (const float*)d_in[3];
    const float* w32   = (const float*)d_in[4];
    const float* gate  = (const float*)d_in[5];
    const float* noise = (const float*)d_in[6];
    float* out = (float*)d_out;

    float* ws    = (float*)d_ws;
    float* Cbuf  = ws;
    float* S1buf = ws + 39936;
    float* sum1  = ws + 41184;
    float* sum2  = ws + 41312;
    uint32_t* Whp = (uint32_t*)(ws + 41440);
    uint32_t* Wlp = (uint32_t*)(ws + 61408);
    float* biasb = ws + 81376;

    hipMemsetAsync(d_ws, 0, 41440 * sizeof(float), stream);
    k_stats<<<dim3(S_CHUNKS, F_DIM), 256, 0, stream>>>(emb, Cbuf, S1buf);
    k_reduce_stats<<<F_DIM, 128, 0, stream>>>(Cbuf, S1buf, w4, w8, w16, w32, sum1, sum2);
    k_finalize<<<1, 256, 0, stream>>>(sum1, sum2, gate, noise, w4, w8, w16, w32, Whp, Wlp, biasb);
    k_apply<<<dim3(A_CHUNKS, F_DIM), 256, 0, stream>>>(emb, Whp, Wlp, biasb, out);
}

// Round 3
// 67.521 us; speedup vs baseline: 6.5545x; 1.7711x over previous
//
#include <hip/hip_runtime.h>
#include <cstdint>
#include <cstddef>

#define F_DIM 39
#define E_DIM 32
#define B_DIM 16384
#define ROWSTRIDE (F_DIM * E_DIM)   // 1248 floats per b row
#define EPS_BN 1e-5f
#define EPS_G 1e-10f

typedef _Float16 f16x8 __attribute__((ext_vector_type(8)));
typedef float f32x16 __attribute__((ext_vector_type(16)));

union H8 { _Float16 h[8]; f16x8 v; uint32_t u[4]; };

// workspace layout (float units):
//   [0,      39936) : C[f][i][j]   (39*1024)  -- zeroed each launch
//   [39936,  41184) : S1[f][i]     (39*32)    -- zeroed each launch
//   [41184,  41312) : sum1[c][e]   (4*32)     -- zeroed each launch
//   [41312,  41440) : sum2[c][e]   (4*32)     -- zeroed each launch
//   [41440,  61408) : Whp[f][16][32] packed f16-hi pairs (uint32)
//   [61408,  81376) : Wlp[f][16][32] packed f16-lo pairs (uint32)
//   [81376,  82624) : bias[f][e]   (39*32)

// ---------------- pass 1: C_f = X_f^T X_f via MFMA (f16 split) ----------------
#define S_CHUNKS 32
#define S_RPB (B_DIM / S_CHUNKS)     // 512 rows/block; 128 rows/wave; 8 K-steps of 16

__global__ __launch_bounds__(256) void k_stats(const float* __restrict__ emb,
                                               float* __restrict__ Cbuf,
                                               float* __restrict__ S1buf) {
    const int f = blockIdx.y;
    const int tid = threadIdx.x;
    const int wave = tid >> 6;
    const int l = tid & 63;
    const int g = l >> 5;        // half-wave (k-group)
    const int c = l & 31;        // column i of X (= m and n of MFMA)

    __shared__ float ldsC[4][1024];

    f32x16 acc;
#pragma unroll
    for (int i = 0; i < 16; ++i) acc[i] = 0.f;
    float s1 = 0.f;

    const int rbase = blockIdx.x * S_RPB + wave * (S_RPB / 4);
    const float* p = emb + (size_t)(rbase + 8 * g) * ROWSTRIDE + f * E_DIM + c;

    for (int t = 0; t < (S_RPB / 4) / 16; ++t) {   // 8 steps, 16 rows each
        float x[8];
#pragma unroll
        for (int e = 0; e < 8; ++e) x[e] = p[(size_t)e * ROWSTRIDE];
        H8 fh, fl;
#pragma unroll
        for (int e = 0; e < 8; ++e) {
            const _Float16 hh = (_Float16)x[e];
            fh.h[e] = hh;
            fl.h[e] = (_Float16)(x[e] - (float)hh);
            s1 += x[e];
        }
        // same fragment feeds A and B: C += Xh^T Xh + Xh^T Xl + Xl^T Xh
        acc = __builtin_amdgcn_mfma_f32_32x32x16_f16(fh.v, fh.v, acc, 0, 0, 0);
        acc = __builtin_amdgcn_mfma_f32_32x32x16_f16(fh.v, fl.v, acc, 0, 0, 0);
        acc = __builtin_amdgcn_mfma_f32_32x32x16_f16(fl.v, fh.v, acc, 0, 0, 0);
        p += (size_t)16 * ROWSTRIDE;
    }

    // D layout (HW-verified): col = lane&31, row = (r&3) + 8*(r>>2) + 4*(lane>>5)
#pragma unroll
    for (int r = 0; r < 16; ++r) {
        const int mrow = (r & 3) + 8 * (r >> 2) + 4 * g;
        ldsC[wave][mrow * 32 + c] = acc[r];
    }
    s1 += __shfl_xor(s1, 32, 64);
    __syncthreads();
    for (int idx = tid; idx < 1024; idx += 256) {
        const float s = ldsC[0][idx] + ldsC[1][idx] + ldsC[2][idx] + ldsC[3][idx];
        unsafeAtomicAdd(&Cbuf[f * 1024 + idx], s);
    }
    if (l < 32) unsafeAtomicAdd(&S1buf[f * 32 + c], s1);
}

// ------------- glue A: per-f quadratic forms -> per-(c,e) sums -------------
__global__ __launch_bounds__(128) void k_reduce_stats(
    const float* __restrict__ Cbuf, const float* __restrict__ S1buf,
    const float* __restrict__ w4, const float* __restrict__ w8,
    const float* __restrict__ w16, const float* __restrict__ w32,
    float* __restrict__ sum1, float* __restrict__ sum2) {
    const int f = blockIdx.x;
    const int tid = threadIdx.x;
    const int cc = tid >> 5;
    const int e = tid & 31;

    __shared__ float ldsC[1024];
    __shared__ float ldsS[32];
    for (int idx = tid; idx < 1024; idx += 128) ldsC[idx] = Cbuf[f * 1024 + idx];
    if (tid < 32) ldsS[tid] = S1buf[f * 32 + tid];
    __syncthreads();

    const int d = 4 << cc;
    const float* w = (cc == 0) ? w4 : (cc == 1) ? w8 : (cc == 2) ? w16 : w32;
    w += (size_t)f * d * E_DIM;

    float wcol[32];
#pragma unroll
    for (int i = 0; i < 32; ++i)
        wcol[i] = (i < d) ? w[(size_t)i * E_DIM + e] : 0.f;

    float m1 = 0.f;
#pragma unroll
    for (int i = 0; i < 32; ++i) m1 = fmaf(ldsS[i], wcol[i], m1);

    float m2 = 0.f;
#pragma unroll
    for (int i = 0; i < 32; ++i) {
        float ti = 0.f;
#pragma unroll
        for (int j = 0; j < 32; ++j) ti = fmaf(ldsC[i * 32 + j], wcol[j], ti);
        m2 = fmaf(ti, wcol[i], m2);
    }
    unsafeAtomicAdd(&sum1[cc * 32 + e], m1);
    unsafeAtomicAdd(&sum2[cc * 32 + e], m2);
}

// ------------- glue B (parallel): per-f W_eff + bias build -------------
// One block per field f. Each block redundantly computes the 128 inv/mu
// values and its own 4 gumbel gates (trivial), then builds Weff[f]/bias[f].
__global__ __launch_bounds__(256) void k_build(
    const float* __restrict__ sum1, const float* __restrict__ sum2,
    const float* __restrict__ gate, const float* __restrict__ noise,
    const float* __restrict__ w4, const float* __restrict__ w8,
    const float* __restrict__ w16, const float* __restrict__ w32,
    uint32_t* __restrict__ Whp, uint32_t* __restrict__ Wlp,
    float* __restrict__ biasb) {
    const int f = blockIdx.x;
    const int tid = threadIdx.x;
    __shared__ float inv_s[4][32];
    __shared__ float mu_s[4][32];
    __shared__ float gate_s[4];

    if (tid < 128) {
        const int cc = tid >> 5, e = tid & 31;
        const float invBF = 1.0f / ((float)B_DIM * (float)F_DIM);
        const float mu = sum1[tid] * invBF;
        const float ey2 = sum2[tid] * invBF;
        const float var = ey2 - mu * mu;
        inv_s[cc][e] = rsqrtf(var + EPS_BN);
        mu_s[cc][e] = mu;
    }
    if (tid == 0) {
        float lg[4], mx = -1e30f;
#pragma unroll
        for (int cc = 0; cc < 4; ++cc) {
            const float u = noise[f * 4 + cc];
            const float gg = -logf(-logf(u + EPS_G) + EPS_G);
            lg[cc] = gate[f * 4 + cc] + gg;
            mx = fmaxf(mx, lg[cc]);
        }
        float se = 0.f;
#pragma unroll
        for (int cc = 0; cc < 4; ++cc) { lg[cc] = expf(lg[cc] - mx); se += lg[cc]; }
#pragma unroll
        for (int cc = 0; cc < 4; ++cc) gate_s[cc] = 0.25f * lg[cc] / se;
    }
    __syncthreads();

    // Weff[f][i][e] packed as (i even, i odd) f16 pairs, split hi/lo
    for (int idx = tid; idx < 512; idx += 256) {
        const int kp = idx >> 5;     // pair index 0..15
        const int e = idx & 31;
        const int i0 = kp * 2;
        float w0 = 0.f, w1 = 0.f;
#pragma unroll
        for (int cc = 0; cc < 4; ++cc) {
            const int d = 4 << cc;
            if (i0 < d) {
                const float* w = (cc == 0) ? w4 : (cc == 1) ? w8 : (cc == 2) ? w16 : w32;
                const float gi = gate_s[cc] * inv_s[cc][e];
                const size_t base = ((size_t)f * d + i0) * E_DIM + e;
                w0 = fmaf(gi, w[base], w0);
                w1 = fmaf(gi, w[base + E_DIM], w1);
            }
        }
        union { _Float16 h[2]; uint32_t u; } ph, pl;
        const _Float16 h0 = (_Float16)w0, h1 = (_Float16)w1;
        ph.h[0] = h0; ph.h[1] = h1;
        pl.h[0] = (_Float16)(w0 - (float)h0);
        pl.h[1] = (_Float16)(w1 - (float)h1);
        Whp[f * 512 + idx] = ph.u;
        Wlp[f * 512 + idx] = pl.u;
    }
    if (tid < E_DIM) {
        float a = 0.f;
#pragma unroll
        for (int cc = 0; cc < 4; ++cc)
            a = fmaf(gate_s[cc], inv_s[cc][tid] * mu_s[cc][tid], a);
        biasb[f * E_DIM + tid] = a;
    }
}

// ---------------- pass 2: Out_f = X_f * Weff_f - bias via MFMA ----------------
#define A_CHUNKS 64
#define A_RPB (B_DIM / A_CHUNKS)    // 256 rows/block; 64/wave = 2 tiles of 32

__global__ __launch_bounds__(256) void k_apply(const float* __restrict__ emb,
                                               const uint32_t* __restrict__ Whp,
                                               const uint32_t* __restrict__ Wlp,
                                               const float* __restrict__ biasb,
                                               float* __restrict__ out) {
    const int f = blockIdx.y;
    const int tid = threadIdx.x;
    const int wave = tid >> 6;
    const int l = tid & 63;
    const int g = l >> 5;
    const int c = l & 31;        // m (b-row in tile) for A, n (=e) for B/D

    // B-operand fragments: k = 16q + 8g + 2p + h  <->  Whp word kp = 8q + 4g + p
    H8 wh[2], wl[2];
#pragma unroll
    for (int q = 0; q < 2; ++q)
#pragma unroll
        for (int pp = 0; pp < 4; ++pp) {
            const int kp = 8 * q + 4 * g + pp;
            wh[q].u[pp] = Whp[f * 512 + kp * 32 + c];
            wl[q].u[pp] = Wlp[f * 512 + kp * 32 + c];
        }
    const float be = biasb[f * 32 + c];

    const int wbase = blockIdx.x * A_RPB + wave * (A_RPB / 4);
#pragma unroll
    for (int t = 0; t < (A_RPB / 4) / 32; ++t) {
        const int b0 = wbase + t * 32;
        const float4* pa = reinterpret_cast<const float4*>(
            emb + (size_t)(b0 + c) * ROWSTRIDE + f * E_DIM + 8 * g);
        f32x16 acc;
#pragma unroll
        for (int i = 0; i < 16; ++i) acc[i] = 0.f;
#pragma unroll
        for (int q = 0; q < 2; ++q) {
            const float4 v0 = pa[4 * q];
            const float4 v1 = pa[4 * q + 1];
            const float x[8] = {v0.x, v0.y, v0.z, v0.w, v1.x, v1.y, v1.z, v1.w};
            H8 ah, al;
#pragma unroll
            for (int e = 0; e < 8; ++e) {
                const _Float16 hh = (_Float16)x[e];
                ah.h[e] = hh;
                al.h[e] = (_Float16)(x[e] - (float)hh);
            }
            acc = __builtin_amdgcn_mfma_f32_32x32x16_f16(ah.v, wh[q].v, acc, 0, 0, 0);
            acc = __builtin_amdgcn_mfma_f32_32x32x16_f16(ah.v, wl[q].v, acc, 0, 0, 0);
            acc = __builtin_amdgcn_mfma_f32_32x32x16_f16(al.v, wh[q].v, acc, 0, 0, 0);
        }
        float* po = out + (size_t)b0 * ROWSTRIDE + f * E_DIM + c;
#pragma unroll
        for (int r = 0; r < 16; ++r) {
            const int mrow = (r & 3) + 8 * (r >> 2) + 4 * g;
            po[(size_t)mrow * ROWSTRIDE] = acc[r] - be;
        }
    }
}

extern "C" void kernel_launch(void* const* d_in, const int* in_sizes, int n_in,
                              void* d_out, int out_size, void* d_ws, size_t ws_size,
                              hipStream_t stream) {
    const float* emb   = (const float*)d_in[0];
    const float* w4    = (const float*)d_in[1];
    const float* w8    = (const float*)d_in[2];
    const float* w16   = (const float*)d_in[3];
    const float* w32   = (const float*)d_in[4];
    const float* gate  = (const float*)d_in[5];
    const float* noise = (const float*)d_in[6];
    float* out = (float*)d_out;

    float* ws    = (float*)d_ws;
    float* Cbuf  = ws;
    float* S1buf = ws + 39936;
    float* sum1  = ws + 41184;
    float* sum2  = ws + 41312;
    uint32_t* Whp = (uint32_t*)(ws + 41440);
    uint32_t* Wlp = (uint32_t*)(ws + 61408);
    float* biasb = ws + 81376;

    hipMemsetAsync(d_ws, 0, 41440 * sizeof(float), stream);
    k_stats<<<dim3(S_CHUNKS, F_DIM), 256, 0, stream>>>(emb, Cbuf, S1buf);
    k_reduce_stats<<<F_DIM, 128, 0, stream>>>(Cbuf, S1buf, w4, w8, w16, w32, sum1, sum2);
    k_build<<<F_DIM, 256, 0, stream>>>(sum1, sum2, gate, noise, w4, w8, w16, w32, Whp, Wlp, biasb);
    k_apply<<<dim3(A_CHUNKS, F_DIM), 256, 0, stream>>>(emb, Whp, Wlp, biasb, out);
}

// Round 4
// 61.970 us; speedup vs baseline: 7.1417x; 1.0896x over previous
//
#include <hip/hip_runtime.h>
#include <cstdint>
#include <cstddef>

#define F_DIM 39
#define E_DIM 32
#define B_DIM 16384
#define ROWSTRIDE (F_DIM * E_DIM)   // 1248 floats per b row
#define EPS_BN 1e-5f
#define EPS_G 1e-10f

typedef _Float16 f16x8 __attribute__((ext_vector_type(8)));
typedef float f32x16 __attribute__((ext_vector_type(16)));

union H8 { _Float16 h[8]; f16x8 v; uint32_t u[4]; };

// workspace layout (float units):
//   [0,       1277952) : Cpart[f][chunk][1024]  (39*32*1024) -- fully overwritten
//   [1277952, 1317888) : S1part[f][chunk][32]   (39*32*32)   -- fully overwritten
//   [1317888, 1322880) : m1f[f][128]            (39*128)     -- fully overwritten
//   [1322880, 1327872) : m2f[f][128]            (39*128)     -- fully overwritten
//   [1327872, 1347840) : Whp[f][16][32] packed f16-hi pairs (uint32)
//   [1347840, 1367808) : Wlp[f][16][32] packed f16-lo pairs (uint32)
//   [1367808, 1369056) : bias[f][e]             (39*32)
// No memset needed: every region is fully overwritten each launch.

// ---------------- pass 1: C_f = X_f^T X_f via MFMA (f16 split) ----------------
#define S_CHUNKS 32
#define S_RPB (B_DIM / S_CHUNKS)     // 512 rows/block; 128 rows/wave; 8 K-steps of 16

__global__ __launch_bounds__(256) void k_stats(const float* __restrict__ emb,
                                               float* __restrict__ Cpart,
                                               float* __restrict__ S1part) {
    const int f = blockIdx.y;
    const int chunk = blockIdx.x;
    const int tid = threadIdx.x;
    const int wave = tid >> 6;
    const int l = tid & 63;
    const int g = l >> 5;        // half-wave (k-group)
    const int c = l & 31;        // column i of X (= m and n of MFMA)

    __shared__ float ldsC[4][1024];
    __shared__ float ldsS[4][32];

    f32x16 acc;
#pragma unroll
    for (int i = 0; i < 16; ++i) acc[i] = 0.f;
    float s1 = 0.f;

    const int rbase = chunk * S_RPB + wave * (S_RPB / 4);
    const float* p = emb + (size_t)(rbase + 8 * g) * ROWSTRIDE + f * E_DIM + c;

    for (int t = 0; t < (S_RPB / 4) / 16; ++t) {   // 8 steps, 16 rows each
        float x[8];
#pragma unroll
        for (int e = 0; e < 8; ++e) x[e] = p[(size_t)e * ROWSTRIDE];
        H8 fh, fl;
#pragma unroll
        for (int e = 0; e < 8; ++e) {
            const _Float16 hh = (_Float16)x[e];
            fh.h[e] = hh;
            // store 2*lo: w^T(Xh^TXh + 2*Xh^TXl)w == w^T C_sym w (qform of
            // asymmetric part equals its transpose's) -> one cross MFMA saved
            fl.h[e] = (_Float16)(2.0f * (x[e] - (float)hh));
            s1 += x[e];
        }
        acc = __builtin_amdgcn_mfma_f32_32x32x16_f16(fh.v, fh.v, acc, 0, 0, 0);
        acc = __builtin_amdgcn_mfma_f32_32x32x16_f16(fh.v, fl.v, acc, 0, 0, 0);
        p += (size_t)16 * ROWSTRIDE;
    }

    // D layout (HW-verified): col = lane&31, row = (r&3) + 8*(r>>2) + 4*(lane>>5)
#pragma unroll
    for (int r = 0; r < 16; ++r) {
        const int mrow = (r & 3) + 8 * (r >> 2) + 4 * g;
        ldsC[wave][mrow * 32 + c] = acc[r];
    }
    s1 += __shfl_xor(s1, 32, 64);
    if (g == 0) ldsS[wave][c] = s1;
    __syncthreads();

    // plain stores of per-(f,chunk) partials -- no atomics, no memset needed
    {
        const float4* l0 = reinterpret_cast<const float4*>(ldsC[0]);
        const float4* l1 = reinterpret_cast<const float4*>(ldsC[1]);
        const float4* l2 = reinterpret_cast<const float4*>(ldsC[2]);
        const float4* l3 = reinterpret_cast<const float4*>(ldsC[3]);
        float4 a = l0[tid], b = l1[tid], cc4 = l2[tid], d4 = l3[tid];
        float4 s;
        s.x = a.x + b.x + cc4.x + d4.x;
        s.y = a.y + b.y + cc4.y + d4.y;
        s.z = a.z + b.z + cc4.z + d4.z;
        s.w = a.w + b.w + cc4.w + d4.w;
        reinterpret_cast<float4*>(Cpart)[(size_t)(f * S_CHUNKS + chunk) * 256 + tid] = s;
    }
    if (tid < 32)
        S1part[(size_t)(f * S_CHUNKS + chunk) * 32 + tid] =
            ldsS[0][tid] + ldsS[1][tid] + ldsS[2][tid] + ldsS[3][tid];
}

// ------------- glue A: sum chunk partials, per-f quadratic forms -------------
__global__ __launch_bounds__(256) void k_reduce(
    const float* __restrict__ Cpart, const float* __restrict__ S1part,
    const float* __restrict__ w4, const float* __restrict__ w8,
    const float* __restrict__ w16, const float* __restrict__ w32,
    float* __restrict__ m1f, float* __restrict__ m2f) {
    const int f = blockIdx.x;
    const int tid = threadIdx.x;

    __shared__ float ldsC[1024];
    __shared__ float ldsS[32];
    for (int idx = tid; idx < 1024; idx += 256) {
        float s = 0.f;
#pragma unroll 8
        for (int ch = 0; ch < S_CHUNKS; ++ch)
            s += Cpart[(size_t)(f * S_CHUNKS + ch) * 1024 + idx];
        ldsC[idx] = s;
    }
    if (tid < 32) {
        float s = 0.f;
#pragma unroll 8
        for (int ch = 0; ch < S_CHUNKS; ++ch)
            s += S1part[(size_t)(f * S_CHUNKS + ch) * 32 + tid];
        ldsS[tid] = s;
    }
    __syncthreads();

    if (tid < 128) {
        const int cc = tid >> 5;
        const int e = tid & 31;
        const int d = 4 << cc;
        const float* w = (cc == 0) ? w4 : (cc == 1) ? w8 : (cc == 2) ? w16 : w32;
        w += (size_t)f * d * E_DIM;

        float wcol[32];
#pragma unroll
        for (int i = 0; i < 32; ++i)
            wcol[i] = (i < d) ? w[(size_t)i * E_DIM + e] : 0.f;

        float m1 = 0.f;
#pragma unroll
        for (int i = 0; i < 32; ++i) m1 = fmaf(ldsS[i], wcol[i], m1);

        float m2 = 0.f;
#pragma unroll
        for (int i = 0; i < 32; ++i) {
            float ti = 0.f;
#pragma unroll
            for (int j = 0; j < 32; ++j) ti = fmaf(ldsC[i * 32 + j], wcol[j], ti);
            m2 = fmaf(ti, wcol[i], m2);
        }
        m1f[f * 128 + tid] = m1;
        m2f[f * 128 + tid] = m2;
    }
}

// ------------- glue B (parallel): per-f W_eff + bias build -------------
__global__ __launch_bounds__(256) void k_build(
    const float* __restrict__ m1f, const float* __restrict__ m2f,
    const float* __restrict__ gate, const float* __restrict__ noise,
    const float* __restrict__ w4, const float* __restrict__ w8,
    const float* __restrict__ w16, const float* __restrict__ w32,
    uint32_t* __restrict__ Whp, uint32_t* __restrict__ Wlp,
    float* __restrict__ biasb) {
    const int f = blockIdx.x;
    const int tid = threadIdx.x;
    __shared__ float inv_s[4][32];
    __shared__ float mu_s[4][32];
    __shared__ float gate_s[4];

    if (tid < 128) {
        const int cc = tid >> 5, e = tid & 31;
        float s1 = 0.f, s2 = 0.f;
#pragma unroll
        for (int ff = 0; ff < F_DIM; ++ff) {
            s1 += m1f[ff * 128 + tid];
            s2 += m2f[ff * 128 + tid];
        }
        const float invBF = 1.0f / ((float)B_DIM * (float)F_DIM);
        const float mu = s1 * invBF;
        const float ey2 = s2 * invBF;
        const float var = ey2 - mu * mu;
        inv_s[cc][e] = rsqrtf(var + EPS_BN);
        mu_s[cc][e] = mu;
    }
    if (tid == 0) {
        float lg[4], mx = -1e30f;
#pragma unroll
        for (int cc = 0; cc < 4; ++cc) {
            const float u = noise[f * 4 + cc];
            const float gg = -logf(-logf(u + EPS_G) + EPS_G);
            lg[cc] = gate[f * 4 + cc] + gg;
            mx = fmaxf(mx, lg[cc]);
        }
        float se = 0.f;
#pragma unroll
        for (int cc = 0; cc < 4; ++cc) { lg[cc] = expf(lg[cc] - mx); se += lg[cc]; }
#pragma unroll
        for (int cc = 0; cc < 4; ++cc) gate_s[cc] = 0.25f * lg[cc] / se;
    }
    __syncthreads();

    // Weff[f][i][e] packed as (i even, i odd) f16 pairs, split hi/lo
    for (int idx = tid; idx < 512; idx += 256) {
        const int kp = idx >> 5;     // pair index 0..15
        const int e = idx & 31;
        const int i0 = kp * 2;
        float w0 = 0.f, w1 = 0.f;
#pragma unroll
        for (int cc = 0; cc < 4; ++cc) {
            const int d = 4 << cc;
            if (i0 < d) {
                const float* w = (cc == 0) ? w4 : (cc == 1) ? w8 : (cc == 2) ? w16 : w32;
                const float gi = gate_s[cc] * inv_s[cc][e];
                const size_t base = ((size_t)f * d + i0) * E_DIM + e;
                w0 = fmaf(gi, w[base], w0);
                w1 = fmaf(gi, w[base + E_DIM], w1);
            }
        }
        union { _Float16 h[2]; uint32_t u; } ph, pl;
        const _Float16 h0 = (_Float16)w0, h1 = (_Float16)w1;
        ph.h[0] = h0; ph.h[1] = h1;
        pl.h[0] = (_Float16)(w0 - (float)h0);
        pl.h[1] = (_Float16)(w1 - (float)h1);
        Whp[f * 512 + idx] = ph.u;
        Wlp[f * 512 + idx] = pl.u;
    }
    if (tid < E_DIM) {
        float a = 0.f;
#pragma unroll
        for (int cc = 0; cc < 4; ++cc)
            a = fmaf(gate_s[cc], inv_s[cc][tid] * mu_s[cc][tid], a);
        biasb[f * E_DIM + tid] = a;
    }
}

// ---------------- pass 2: Out_f = X_f * Weff_f - bias via MFMA ----------------
#define A_CHUNKS 64
#define A_RPB (B_DIM / A_CHUNKS)    // 256 rows/block; 64/wave = 2 tiles of 32

__global__ __launch_bounds__(256) void k_apply(const float* __restrict__ emb,
                                               const uint32_t* __restrict__ Whp,
                                               const uint32_t* __restrict__ Wlp,
                                               const float* __restrict__ biasb,
                                               float* __restrict__ out) {
    const int f = blockIdx.y;
    const int tid = threadIdx.x;
    const int wave = tid >> 6;
    const int l = tid & 63;
    const int g = l >> 5;
    const int c = l & 31;        // m (b-row in tile) for A, n (=e) for B/D

    // B-operand fragments: k = 16q + 8g + 2p + h  <->  Whp word kp = 8q + 4g + p
    H8 wh[2], wl[2];
#pragma unroll
    for (int q = 0; q < 2; ++q)
#pragma unroll
        for (int pp = 0; pp < 4; ++pp) {
            const int kp = 8 * q + 4 * g + pp;
            wh[q].u[pp] = Whp[f * 512 + kp * 32 + c];
            wl[q].u[pp] = Wlp[f * 512 + kp * 32 + c];
        }
    const float be = biasb[f * 32 + c];

    const int wbase = blockIdx.x * A_RPB + wave * (A_RPB / 4);
#pragma unroll
    for (int t = 0; t < (A_RPB / 4) / 32; ++t) {
        const int b0 = wbase + t * 32;
        const float4* pa = reinterpret_cast<const float4*>(
            emb + (size_t)(b0 + c) * ROWSTRIDE + f * E_DIM + 8 * g);
        f32x16 acc;
#pragma unroll
        for (int i = 0; i < 16; ++i) acc[i] = 0.f;
#pragma unroll
        for (int q = 0; q < 2; ++q) {
            const float4 v0 = pa[4 * q];
            const float4 v1 = pa[4 * q + 1];
            const float x[8] = {v0.x, v0.y, v0.z, v0.w, v1.x, v1.y, v1.z, v1.w};
            H8 ah, al;
#pragma unroll
            for (int e = 0; e < 8; ++e) {
                const _Float16 hh = (_Float16)x[e];
                ah.h[e] = hh;
                al.h[e] = (_Float16)(x[e] - (float)hh);
            }
            acc = __builtin_amdgcn_mfma_f32_32x32x16_f16(ah.v, wh[q].v, acc, 0, 0, 0);
            acc = __builtin_amdgcn_mfma_f32_32x32x16_f16(ah.v, wl[q].v, acc, 0, 0, 0);
            acc = __builtin_amdgcn_mfma_f32_32x32x16_f16(al.v, wh[q].v, acc, 0, 0, 0);
        }
        float* po = out + (size_t)b0 * ROWSTRIDE + f * E_DIM + c;
#pragma unroll
        for (int r = 0; r < 16; ++r) {
            const int mrow = (r & 3) + 8 * (r >> 2) + 4 * g;
            __builtin_nontemporal_store(acc[r] - be, po + (size_t)mrow * ROWSTRIDE);
        }
    }
}

extern "C" void kernel_launch(void* const* d_in, const int* in_sizes, int n_in,
                              void* d_out, int out_size, void* d_ws, size_t ws_size,
                              hipStream_t stream) {
    const float* emb   = (const float*)d_in[0];
    const float* w4    = (const float*)d_in[1];
    const float* w8    = (const float*)d_in[2];
    const float* w16   = (const float*)d_in[3];
    const float* w32   = (const float*)d_in[4];
    const float* gate  = (const float*)d_in[5];
    const float* noise = (const float*)d_in[6];
    float* out = (float*)d_out;

    float* ws     = (float*)d_ws;
    float* Cpart  = ws;                 // 39*32*1024
    float* S1part = ws + 1277952;       // 39*32*32
    float* m1f    = ws + 1317888;       // 39*128
    float* m2f    = ws + 1322880;       // 39*128
    uint32_t* Whp = (uint32_t*)(ws + 1327872);   // 39*512
    uint32_t* Wlp = (uint32_t*)(ws + 1347840);   // 39*512
    float* biasb  = ws + 1367808;       // 39*32

    k_stats<<<dim3(S_CHUNKS, F_DIM), 256, 0, stream>>>(emb, Cpart, S1part);
    k_reduce<<<F_DIM, 256, 0, stream>>>(Cpart, S1part, w4, w8, w16, w32, m1f, m2f);
    k_build<<<F_DIM, 256, 0, stream>>>(m1f, m2f, gate, noise, w4, w8, w16, w32, Whp, Wlp, biasb);
    k_apply<<<dim3(A_CHUNKS, F_DIM), 256, 0, stream>>>(emb, Whp, Wlp, biasb, out);
}

// Round 5
// 55.928 us; speedup vs baseline: 7.9132x; 1.1080x over previous
//
#include <hip/hip_runtime.h>
#include <cstdint>
#include <cstddef>

#define F_DIM 39
#define E_DIM 32
#define B_DIM 16384
#define ROWSTRIDE 1248              // 39*32 floats per b row
#define EPS_BN 1e-5f
#define EPS_G 1e-10f

typedef _Float16 f16x8 __attribute__((ext_vector_type(8)));
typedef float f32x16 __attribute__((ext_vector_type(16)));
union H8 { _Float16 h[8]; f16x8 v; uint32_t u[4]; };

// workspace layout (float units), every region fully overwritten each launch:
//   [0,      319488) : qpart[f*32+chunk][256]  ({Sy(128), Sy2(128)} per block)
//   [319488, 329472) : m12f[f][256]
//   [329472, 349440) : Whp[f][16][32] packed f16-hi pairs (uint32)
//   [349440, 369408) : Wlp[f][16][32] packed f16-lo pairs (uint32)
//   [369408, 370656) : bias[f][e]

// ---- pass 1: per-(f,chunk) Sy, Sy2 of candidate outputs, via MFMA Y-tiles ----
#define S_CHUNKS 32
#define S_RPB 512                    // rows/block; 128/wave; 4 tiles of 32

__global__ __launch_bounds__(256) void k_stats(const float* __restrict__ emb,
    const float* __restrict__ w4, const float* __restrict__ w8,
    const float* __restrict__ w16, const float* __restrict__ w32,
    float* __restrict__ qpart) {
    const int f = blockIdx.y;
    const int chunk = blockIdx.x;
    const int tid = threadIdx.x;
    const int wave = tid >> 6;
    const int l = tid & 63;
    const int g = l >> 5;
    const int c = l & 31;            // column: m-row for A, n (=e) for B/D

    // 5 non-zero B-fragments: idx -> (cc,kq): 0:(0,0) 1:(1,0) 2:(2,0) 3:(3,0) 4:(3,1)
    // k-slot p of half g holds k = 16*kq + 8*g + p (same convention as k_apply,
    // HW-validated by rounds 2-4 passing).
    H8 wf[5];
    {
        const float* wt[4] = {w4, w8, w16, w32};
#pragma unroll
        for (int idx = 0; idx < 5; ++idx) {
            const int cc = (idx < 4) ? idx : 3;
            const int kq = (idx < 4) ? 0 : 1;
            const int d = 4 << cc;
            const float* w = wt[cc] + (size_t)f * d * E_DIM;
#pragma unroll
            for (int p = 0; p < 8; ++p) {
                const int k = 16 * kq + 8 * g + p;
                wf[idx].h[p] = (k < d) ? (_Float16)w[k * E_DIM + c] : (_Float16)0.f;
            }
        }
    }

    float ysum[4] = {0.f, 0.f, 0.f, 0.f};
    float y2s[4] = {0.f, 0.f, 0.f, 0.f};
    const float* prow = emb + (size_t)(chunk * S_RPB + wave * 128 + c) * ROWSTRIDE + f * E_DIM;

#pragma unroll
    for (int t = 0; t < 4; ++t) {
        const float4* pa = reinterpret_cast<const float4*>(prow);
        const float4 v0 = pa[2 * g], v1 = pa[2 * g + 1];
        const float4 v2 = pa[4 + 2 * g], v3 = pa[4 + 2 * g + 1];
        H8 a0, a1;
        a0.h[0] = (_Float16)v0.x; a0.h[1] = (_Float16)v0.y;
        a0.h[2] = (_Float16)v0.z; a0.h[3] = (_Float16)v0.w;
        a0.h[4] = (_Float16)v1.x; a0.h[5] = (_Float16)v1.y;
        a0.h[6] = (_Float16)v1.z; a0.h[7] = (_Float16)v1.w;
        a1.h[0] = (_Float16)v2.x; a1.h[1] = (_Float16)v2.y;
        a1.h[2] = (_Float16)v2.z; a1.h[3] = (_Float16)v2.w;
        a1.h[4] = (_Float16)v3.x; a1.h[5] = (_Float16)v3.y;
        a1.h[6] = (_Float16)v3.z; a1.h[7] = (_Float16)v3.w;

#pragma unroll
        for (int cc = 0; cc < 4; ++cc) {
            f32x16 acc;
#pragma unroll
            for (int i = 0; i < 16; ++i) acc[i] = 0.f;
            acc = __builtin_amdgcn_mfma_f32_32x32x16_f16(a0.v, wf[cc].v, acc, 0, 0, 0);
            if (cc == 3)
                acc = __builtin_amdgcn_mfma_f32_32x32x16_f16(a1.v, wf[4].v, acc, 0, 0, 0);
            // column sums: D col = c for this lane; row indices irrelevant.
#pragma unroll
            for (int r = 0; r < 16; ++r) {
                ysum[cc] += acc[r];
                y2s[cc] = fmaf(acc[r], acc[r], y2s[cc]);
            }
        }
        prow += (size_t)32 * ROWSTRIDE;
    }

#pragma unroll
    for (int cc = 0; cc < 4; ++cc) {
        ysum[cc] += __shfl_xor(ysum[cc], 32, 64);
        y2s[cc] += __shfl_xor(y2s[cc], 32, 64);
    }
    __shared__ float ldsY[4][128];
    __shared__ float ldsQ[4][128];
    if (l < 32) {
#pragma unroll
        for (int cc = 0; cc < 4; ++cc) {
            ldsY[wave][cc * 32 + c] = ysum[cc];
            ldsQ[wave][cc * 32 + c] = y2s[cc];
        }
    }
    __syncthreads();
    if (tid < 128) {
        const float m1 = ldsY[0][tid] + ldsY[1][tid] + ldsY[2][tid] + ldsY[3][tid];
        const float m2 = ldsQ[0][tid] + ldsQ[1][tid] + ldsQ[2][tid] + ldsQ[3][tid];
        float* qp = qpart + (size_t)(f * S_CHUNKS + chunk) * 256;
        qp[tid] = m1;
        qp[128 + tid] = m2;
    }
}

// ---- glue A: per-f chunk-sum (trivial) ----
__global__ __launch_bounds__(256) void k_mid(const float* __restrict__ qpart,
                                             float* __restrict__ m12f) {
    const int f = blockIdx.x;
    const int tid = threadIdx.x;
    float s = 0.f;
    const float* qp = qpart + (size_t)f * S_CHUNKS * 256 + tid;
#pragma unroll 8
    for (int ch = 0; ch < S_CHUNKS; ++ch) s += qp[(size_t)ch * 256];
    m12f[f * 256 + tid] = s;
}

// ---- glue B: stats + gumbel gates -> packed f16 W_eff + bias (per f) ----
__global__ __launch_bounds__(256) void k_build(
    const float* __restrict__ m12f,
    const float* __restrict__ gate, const float* __restrict__ noise,
    const float* __restrict__ w4, const float* __restrict__ w8,
    const float* __restrict__ w16, const float* __restrict__ w32,
    uint32_t* __restrict__ Whp, uint32_t* __restrict__ Wlp,
    float* __restrict__ biasb) {
    const int f = blockIdx.x;
    const int tid = threadIdx.x;
    __shared__ float ldsT[256];
    __shared__ float inv_s[4][32];
    __shared__ float mu_s[4][32];
    __shared__ float gate_s[4];

    {
        float s = 0.f;
#pragma unroll
        for (int ff = 0; ff < F_DIM; ++ff) s += m12f[ff * 256 + tid];
        ldsT[tid] = s;
    }
    if (tid == 0) {
        float lg[4], mx = -1e30f;
#pragma unroll
        for (int cc = 0; cc < 4; ++cc) {
            const float u = noise[f * 4 + cc];
            const float gg = -logf(-logf(u + EPS_G) + EPS_G);
            lg[cc] = gate[f * 4 + cc] + gg;
            mx = fmaxf(mx, lg[cc]);
        }
        float se = 0.f;
#pragma unroll
        for (int cc = 0; cc < 4; ++cc) { lg[cc] = expf(lg[cc] - mx); se += lg[cc]; }
#pragma unroll
        for (int cc = 0; cc < 4; ++cc) gate_s[cc] = 0.25f * lg[cc] / se;
    }
    __syncthreads();
    if (tid < 128) {
        const int cc = tid >> 5, e = tid & 31;
        const float invBF = 1.0f / ((float)B_DIM * (float)F_DIM);
        const float mu = ldsT[tid] * invBF;
        const float ey2 = ldsT[128 + tid] * invBF;
        const float var = ey2 - mu * mu;
        inv_s[cc][e] = rsqrtf(var + EPS_BN);
        mu_s[cc][e] = mu;
    }
    __syncthreads();

    // Weff[f][i][e] packed as (i even, i odd) f16 pairs, split hi/lo
    for (int idx = tid; idx < 512; idx += 256) {
        const int kp = idx >> 5;
        const int e = idx & 31;
        const int i0 = kp * 2;
        float w0 = 0.f, w1 = 0.f;
#pragma unroll
        for (int cc = 0; cc < 4; ++cc) {
            const int d = 4 << cc;
            if (i0 < d) {
                const float* w = (cc == 0) ? w4 : (cc == 1) ? w8 : (cc == 2) ? w16 : w32;
                const float gi = gate_s[cc] * inv_s[cc][e];
                const size_t base = ((size_t)f * d + i0) * E_DIM + e;
                w0 = fmaf(gi, w[base], w0);
                w1 = fmaf(gi, w[base + E_DIM], w1);
            }
        }
        union { _Float16 h[2]; uint32_t u; } ph, pl;
        const _Float16 h0 = (_Float16)w0, h1 = (_Float16)w1;
        ph.h[0] = h0; ph.h[1] = h1;
        pl.h[0] = (_Float16)(w0 - (float)h0);
        pl.h[1] = (_Float16)(w1 - (float)h1);
        Whp[f * 512 + idx] = ph.u;
        Wlp[f * 512 + idx] = pl.u;
    }
    if (tid < E_DIM) {
        float a = 0.f;
#pragma unroll
        for (int cc = 0; cc < 4; ++cc)
            a = fmaf(gate_s[cc], inv_s[cc][tid] * mu_s[cc][tid], a);
        biasb[f * E_DIM + tid] = a;
    }
}

// ---- pass 2: Out_f = X_f * Weff_f - bias via MFMA (f16 split, unchanged) ----
#define A_CHUNKS 64
#define A_RPB (B_DIM / A_CHUNKS)     // 256 rows/block; 64/wave = 2 tiles of 32

__global__ __launch_bounds__(256) void k_apply(const float* __restrict__ emb,
                                               const uint32_t* __restrict__ Whp,
                                               const uint32_t* __restrict__ Wlp,
                                               const float* __restrict__ biasb,
                                               float* __restrict__ out) {
    const int f = blockIdx.y;
    const int tid = threadIdx.x;
    const int wave = tid >> 6;
    const int l = tid & 63;
    const int g = l >> 5;
    const int c = l & 31;

    H8 wh[2], wl[2];
#pragma unroll
    for (int q = 0; q < 2; ++q)
#pragma unroll
        for (int pp = 0; pp < 4; ++pp) {
            const int kp = 8 * q + 4 * g + pp;
            wh[q].u[pp] = Whp[f * 512 + kp * 32 + c];
            wl[q].u[pp] = Wlp[f * 512 + kp * 32 + c];
        }
    const float be = biasb[f * 32 + c];

    const int wbase = blockIdx.x * A_RPB + wave * (A_RPB / 4);
#pragma unroll
    for (int t = 0; t < (A_RPB / 4) / 32; ++t) {
        const int b0 = wbase + t * 32;
        const float4* pa = reinterpret_cast<const float4*>(
            emb + (size_t)(b0 + c) * ROWSTRIDE + f * E_DIM + 8 * g);
        f32x16 acc;
#pragma unroll
        for (int i = 0; i < 16; ++i) acc[i] = 0.f;
#pragma unroll
        for (int q = 0; q < 2; ++q) {
            const float4 v0 = pa[4 * q];
            const float4 v1 = pa[4 * q + 1];
            const float x[8] = {v0.x, v0.y, v0.z, v0.w, v1.x, v1.y, v1.z, v1.w};
            H8 ah, al;
#pragma unroll
            for (int e = 0; e < 8; ++e) {
                const _Float16 hh = (_Float16)x[e];
                ah.h[e] = hh;
                al.h[e] = (_Float16)(x[e] - (float)hh);
            }
            acc = __builtin_amdgcn_mfma_f32_32x32x16_f16(ah.v, wh[q].v, acc, 0, 0, 0);
            acc = __builtin_amdgcn_mfma_f32_32x32x16_f16(ah.v, wl[q].v, acc, 0, 0, 0);
            acc = __builtin_amdgcn_mfma_f32_32x32x16_f16(al.v, wh[q].v, acc, 0, 0, 0);
        }
        float* po = out + (size_t)b0 * ROWSTRIDE + f * E_DIM + c;
#pragma unroll
        for (int r = 0; r < 16; ++r) {
            const int mrow = (r & 3) + 8 * (r >> 2) + 4 * g;
            __builtin_nontemporal_store(acc[r] - be, po + (size_t)mrow * ROWSTRIDE);
        }
    }
}

extern "C" void kernel_launch(void* const* d_in, const int* in_sizes, int n_in,
                              void* d_out, int out_size, void* d_ws, size_t ws_size,
                              hipStream_t stream) {
    const float* emb   = (const float*)d_in[0];
    const float* w4    = (const float*)d_in[1];
    const float* w8    = (const float*)d_in[2];
    const float* w16   = (const float*)d_in[3];
    const float* w32   = (const float*)d_in[4];
    const float* gate  = (const float*)d_in[5];
    const float* noise = (const float*)d_in[6];
    float* out = (float*)d_out;

    float* ws     = (float*)d_ws;
    float* qpart  = ws;                          // 1248*256
    float* m12f   = ws + 319488;                 // 39*256
    uint32_t* Whp = (uint32_t*)(ws + 329472);    // 39*512
    uint32_t* Wlp = (uint32_t*)(ws + 349440);    // 39*512
    float* biasb  = ws + 369408;                 // 39*32

    k_stats<<<dim3(S_CHUNKS, F_DIM), 256, 0, stream>>>(emb, w4, w8, w16, w32, qpart);
    k_mid<<<F_DIM, 256, 0, stream>>>(qpart, m12f);
    k_build<<<F_DIM, 256, 0, stream>>>(m12f, gate, noise, w4, w8, w16, w32, Whp, Wlp, biasb);
    k_apply<<<dim3(A_CHUNKS, F_DIM), 256, 0, stream>>>(emb, Whp, Wlp, biasb, out);
}